// Round 13
// baseline (1142.699 us; speedup 1.0000x reference)
//
#include <hip/hip_runtime.h>
#include <cmath>

#define D_ 4096
#define H_ 32
#define HD_ 128
#define B_ 8
#define MAXSEQ_ 2048
#define AL_ 10
#define FF_ 11008
#define SCALE_ 0.08838834764831845f   // 1/sqrt(128)
#define EPS_ 1e-5f
#define PSTRIDE 160                   // attn partial record stride (floats); o[] at +32 (64B aligned)

// ---------- fused: rmsnorm(x) -> xa rows 0..7 ; adapter copy -> xa rows 8..17 ----------
__global__ __launch_bounds__(256) void norm_adapter_k(const float* __restrict__ x,
                                                      const float* __restrict__ w,
                                                      const float* __restrict__ adapter,
                                                      float* __restrict__ xa) {
  int b = blockIdx.x, tid = threadIdx.x;
  if (b < 8) {
    const float* xr = x + (size_t)b * D_;
    float ss = 0.f;
    for (int i = tid; i < D_; i += 256) { float v = xr[i]; ss += v * v; }
    __shared__ float red[256];
    red[tid] = ss; __syncthreads();
    for (int s = 128; s; s >>= 1) { if (tid < s) red[tid] += red[tid + s]; __syncthreads(); }
    float r = rsqrtf(red[0] / (float)D_ + EPS_);
    float* o = xa + (size_t)b * D_;
    for (int i = tid; i < D_; i += 256) o[i] = xr[i] * r * w[i];
  } else {
    int r = b - 8;
    const float4* src = (const float4*)(adapter + (size_t)r * D_);
    float4* dst = (float4*)(xa + (size_t)(8 + r) * D_);
    for (int i = tid; i < D_ / 4; i += 256) dst[i] = src[i];
  }
}

// ------------- row-split split-K GEMV: 4 waves/block, each wave owns <=NR rows -------------
template<int NR, int ROWS, int CHUNK, int UNROLL>
__device__ __forceinline__ void gemv_core(
    const float4* __restrict__ W4, const float (*xs)[ROWS],
    int i0, int N4, int j4, int r0, float* __restrict__ P, size_t pb, int N) {
  float4 acc[NR];
#pragma unroll
  for (int r = 0; r < NR; ++r) acc[r] = make_float4(0.f, 0.f, 0.f, 0.f);
  for (int iu = 0; iu < CHUNK; iu += UNROLL) {
    float4 w[UNROLL];
#pragma unroll
    for (int u = 0; u < UNROLL; ++u)
      w[u] = W4[(size_t)(i0 + iu + u) * N4 + j4];
#pragma unroll
    for (int u = 0; u < UNROLL; ++u) {
#pragma unroll
      for (int r = 0; r < NR; ++r) {
        float xv = xs[iu + u][r0 + r];
        acc[r].x += xv * w[u].x; acc[r].y += xv * w[u].y;
        acc[r].z += xv * w[u].z; acc[r].w += xv * w[u].w;
      }
    }
  }
#pragma unroll
  for (int r = 0; r < NR; ++r)
    *(float4*)&P[(pb + r) * (size_t)N + (size_t)4 * j4] = acc[r];
}

// grid = (N4/64, K/CHUNK, nmat); block = 256 (4 waves).
template<int ROWS, int RPG, int CHUNK, int UNROLL>
__global__ __launch_bounds__(256, 1) void gemv_rs(
    const float* __restrict__ X,
    const float* __restrict__ Wa, const float* __restrict__ Wb, const float* __restrict__ Wc,
    float* __restrict__ P, int N, int K) {
  const float* W = (blockIdx.z == 0) ? Wa : (blockIdx.z == 1) ? Wb : Wc;
  __shared__ float xs[CHUNK][ROWS];
  int tid = threadIdx.x;
  int i0 = blockIdx.y * CHUNK;
  for (int idx = tid; idx < ROWS * CHUNK; idx += 256) {
    int r = idx / CHUNK, ii = idx - r * CHUNK;
    xs[ii][r] = X[(size_t)r * K + i0 + ii];
  }
  __syncthreads();
  int wave = tid >> 6, lane = tid & 63;
  int r0 = wave * RPG;
  int N4 = N >> 2;
  int j4 = blockIdx.x * 64 + lane;
  const float4* W4 = (const float4*)W;
  size_t pb = ((size_t)blockIdx.z * gridDim.y + blockIdx.y) * ROWS + r0;
  constexpr int LAST = ROWS - 3 * RPG;
  if (r0 + RPG <= ROWS)
    gemv_core<RPG, ROWS, CHUNK, UNROLL>(W4, xs, i0, N4, j4, r0, P, pb, N);
  else if (LAST > 0)
    gemv_core<(LAST > 0 ? LAST : 1), ROWS, CHUNK, UNROLL>(W4, xs, i0, N4, j4, r0, P, pb, N);
}

// ---- DIAGNOSTIC: FFN gemv repeated 6x in one dispatch (writes identical dummy partials) ----
template<int ROWS, int RPG, int CHUNK, int UNROLL>
__global__ __launch_bounds__(256, 1) void ffn_rep_k(
    const float* __restrict__ X,
    const float* __restrict__ Wa, const float* __restrict__ Wb,
    float* __restrict__ P, int N, int K) {
  const float* W = (blockIdx.z == 0) ? Wa : Wb;
  __shared__ float xs[CHUNK][ROWS];
  int tid = threadIdx.x;
  int by = blockIdx.y & 7;                      // 48 y-blocks -> 6 sweeps of 8 chunks
  int i0 = by * CHUNK;
  for (int idx = tid; idx < ROWS * CHUNK; idx += 256) {
    int r = idx / CHUNK, ii = idx - r * CHUNK;
    xs[ii][r] = X[(size_t)r * K + i0 + ii];
  }
  __syncthreads();
  int wave = tid >> 6, lane = tid & 63;
  int r0 = wave * RPG;
  int N4 = N >> 2;
  int j4 = blockIdx.x * 64 + lane;
  size_t pb = ((size_t)blockIdx.z * 8 + by) * ROWS + r0;
  gemv_core<RPG, ROWS, CHUNK, UNROLL>((const float4*)W, xs, i0, N4, j4, r0, P, pb, N);
}

// ------- QKV reduction over 16 chunks + fused RoPE on q,k rows 0..7 -------
// P: [z(3)][chunk(16)][row(18)][4096]
__global__ __launch_bounds__(256) void reduce3_rope_k(
    const float* __restrict__ P, const float* __restrict__ fc, const float* __restrict__ fs,
    float* __restrict__ Ya, float* __restrict__ Yb, float* __restrict__ Yc) {
  int z = blockIdx.z;
  int i4 = blockIdx.x * 256 + threadIdx.x;      // 18432 float4 per z
  const float4* P4 = (const float4*)P;
  size_t base = (size_t)z * 16 * 18432 + i4;
  float4 s = make_float4(0.f, 0.f, 0.f, 0.f);
#pragma unroll
  for (int c = 0; c < 16; ++c) {
    float4 v = P4[base + (size_t)c * 18432];
    s.x += v.x; s.y += v.y; s.z += v.z; s.w += v.w;
  }
  int row = i4 >> 10;
  if (z < 2 && row < 8) {
    int c0 = (i4 & 1023) << 2;
    int p0 = (c0 & 127) >> 1;
    float ca = fc[p0], sa = fs[p0], cb = fc[p0 + 1], sb = fs[p0 + 1];
    float4 r;
    r.x = s.x * ca - s.y * sa; r.y = s.x * sa + s.y * ca;
    r.z = s.z * cb - s.w * sb; r.w = s.z * sb + s.w * cb;
    s = r;
  }
  float4* Y = (float4*)(z == 0 ? Ya : z == 1 ? Yb : Yc);
  Y[i4] = s;
}

// ------- reduction with residual base: Y = base + sum_c P[c] -------
__global__ __launch_bounds__(256) void reduceB_k(const float* __restrict__ P,
                                                 const float* __restrict__ base,
                                                 float* __restrict__ Y, int n4, int nc) {
  int i4 = blockIdx.x * 256 + threadIdx.x;
  if (i4 >= n4) return;
  const float4* P4 = (const float4*)P;
  float4 s = ((const float4*)base)[i4];
  for (int c = 0; c < nc; ++c) {
    float4 v = P4[(size_t)c * n4 + i4];
    s.x += v.x; s.y += v.y; s.z += v.z; s.w += v.w;
  }
  ((float4*)Y)[i4] = s;
}

// ------- fused: h = x + sum_c P[c] (wo partials) ; hn = rmsnorm(h) -------
// grid = 8 (one per b), block = 1024; P layout [chunk nc][8][4096]
__global__ __launch_bounds__(1024) void h_norm_k(const float* __restrict__ P,
                                                 const float* __restrict__ x,
                                                 const float* __restrict__ w,
                                                 float* __restrict__ hbuf,
                                                 float* __restrict__ hn, int nc) {
  int b = blockIdx.x, tid = threadIdx.x;        // tid = float4 index in row
  const float4* P4 = (const float4*)P;
  float4 s = ((const float4*)x)[b * 1024 + tid];
  for (int c = 0; c < nc; ++c) {
    float4 v = P4[((size_t)c * 8 + b) * 1024 + tid];
    s.x += v.x; s.y += v.y; s.z += v.z; s.w += v.w;
  }
  ((float4*)hbuf)[b * 1024 + tid] = s;
  float ss = s.x * s.x + s.y * s.y + s.z * s.z + s.w * s.w;
  __shared__ float red[1024];
  red[tid] = ss; __syncthreads();
  for (int st = 512; st; st >>= 1) { if (tid < st) red[tid] += red[tid + st]; __syncthreads(); }
  float r = rsqrtf(red[0] / (float)D_ + EPS_);
  float4 wv = ((const float4*)w)[tid];
  float4 o;
  o.x = s.x * r * wv.x; o.y = s.y * r * wv.y; o.z = s.z * r * wv.z; o.w = s.w * r * wv.w;
  ((float4*)hn)[b * 1024 + tid] = o;
}

// ------- FFN: gb = silu(sum P[z=0]) * (sum P[z=1]) ; P [z(2)][chunk(8)][8][11008] -------
__global__ __launch_bounds__(256) void reduce_silu_k(const float* __restrict__ P,
                                                     float* __restrict__ gb) {
  int i4 = blockIdx.x * 256 + threadIdx.x;      // < 22016
  const float4* P4 = (const float4*)P;
  float4 a = make_float4(0.f, 0.f, 0.f, 0.f);
  float4 b = make_float4(0.f, 0.f, 0.f, 0.f);
#pragma unroll
  for (int c = 0; c < 8; ++c) {
    float4 u = P4[(size_t)c * 22016 + i4];
    float4 v = P4[(size_t)(8 + c) * 22016 + i4];
    a.x += u.x; a.y += u.y; a.z += u.z; a.w += u.w;
    b.x += v.x; b.y += v.y; b.z += v.z; b.w += v.w;
  }
  float4 o;
  o.x = (a.x / (1.f + __expf(-a.x))) * b.x;
  o.y = (a.y / (1.f + __expf(-a.y))) * b.y;
  o.z = (a.z / (1.f + __expf(-a.z))) * b.z;
  o.w = (a.w / (1.f + __expf(-a.w))) * b.w;
  ((float4*)gb)[i4] = o;
}

// ---------------- attention pass 1 body (shared by real + diagnostic kernels) ----------------
__device__ __forceinline__ void attn_body(int idx, int tid,
                                          const float* __restrict__ qp,
                                          const float* __restrict__ ck,
                                          const float* __restrict__ cv,
                                          float* __restrict__ part) {
  int c = idx & 7, bh = idx >> 3;
  int h = bh & 31, b = bh >> 5;
  int wave = tid >> 6, lane = tid & 63;
  int half = lane >> 5, l32 = lane & 31;
  int t0 = c * 256 + wave * 64;
  const float4 qv = *(const float4*)&qp[(size_t)b * D_ + h * HD_ + 4 * l32];
  const size_t kvbase = ((size_t)b * MAXSEQ_) * (H_ * HD_) + (size_t)h * HD_ + 4 * l32;
  float m = -INFINITY, l = 0.f;
  float4 o = make_float4(0.f, 0.f, 0.f, 0.f);
#pragma unroll 4
  for (int i = 0; i < 32; ++i) {
    int t = t0 + 2 * i + half;
    size_t off = kvbase + (size_t)t * (H_ * HD_);
    float4 kv = *(const float4*)&ck[off];
    float s = qv.x * kv.x + qv.y * kv.y + qv.z * kv.z + qv.w * kv.w;
    s += __shfl_xor(s, 16); s += __shfl_xor(s, 8);
    s += __shfl_xor(s, 4);  s += __shfl_xor(s, 2); s += __shfl_xor(s, 1);
    s *= SCALE_;
    if (t == MAXSEQ_ - 1) s = -1e30f;     // new token folded in combine
    float mn = fmaxf(m, s);
    float r = __expf(m - mn), p = __expf(s - mn);
    float4 vv = *(const float4*)&cv[off];
    o.x = o.x * r + p * vv.x; o.y = o.y * r + p * vv.y;
    o.z = o.z * r + p * vv.z; o.w = o.w * r + p * vv.w;
    l = l * r + p; m = mn;
  }
  float mo = __shfl_xor(m, 32);
  float M = fmaxf(m, mo);
  float e = __expf(m - M);
  o.x *= e; o.y *= e; o.z *= e; o.w *= e; l *= e;
  o.x += __shfl_xor(o.x, 32); o.y += __shfl_xor(o.y, 32);
  o.z += __shfl_xor(o.z, 32); o.w += __shfl_xor(o.w, 32);
  l += __shfl_xor(l, 32);
  float* po = &part[((size_t)idx * 4 + wave) * PSTRIDE];
  if (lane == 0) { po[0] = M; po[1] = l; }
  if (half == 0) *(float4*)&po[32 + 4 * l32] = o;
}

__global__ __launch_bounds__(256) void attn_partial(
    const float* __restrict__ qp, const float* __restrict__ ck,
    const float* __restrict__ cv, float* __restrict__ part) {
  attn_body(blockIdx.x, threadIdx.x, qp, ck, cv, part);
}

// ---- DIAGNOSTIC: 4 sweeps of attn_partial in ONE dispatch (identical dummy writes) ----
__global__ __launch_bounds__(256) void attn4_k(
    const float* __restrict__ qp, const float* __restrict__ ck,
    const float* __restrict__ cv, float* __restrict__ part) {
  attn_body(blockIdx.x & 2047, threadIdx.x, qp, ck, cv, part);
}

// --- attention pass 2 (shuffle-based): combine 32 partials + new token + adapter + gate ---
__global__ __launch_bounds__(128) void attn_combine(
    const float* __restrict__ part,
    const float* __restrict__ qp,
    const float* __restrict__ kvk,  // rows 0..7 = new k (roped), rows 8..17 = ak
    const float* __restrict__ kvv,  // rows 0..7 = new v,         rows 8..17 = av
    const float* __restrict__ gate,
    float* __restrict__ attn) {
  int bh = blockIdx.x;
  int h = bh & 31, b = bh >> 5;
  int tid = threadIdx.x;            // = d in [0,128)
  int wave = tid >> 6, lane = tid & 63;
  const float* pb = &part[(size_t)bh * 32 * PSTRIDE];
  __shared__ float sm[32], sl[32];
  __shared__ float s2[2][12];
  if (tid < 32) { sm[tid] = pb[tid * PSTRIDE]; sl[tid] = pb[tid * PSTRIDE + 1]; }
  __syncthreads();
  float M = -INFINITY;
  for (int c = 0; c < 32; ++c) M = fmaxf(M, sm[c]);
  float L = 0.f, O = 0.f;
#pragma unroll 4
  for (int c = 0; c < 32; ++c) {
    float e = __expf(sm[c] - M);
    L += e * sl[c];
    O += e * pb[c * PSTRIDE + 32 + tid];
  }
  size_t qi = (size_t)b * D_ + h * HD_ + tid;
  float qd = qp[qi];
  {
    float pr = qd * kvk[qi];
    pr += __shfl_xor(pr, 32); pr += __shfl_xor(pr, 16); pr += __shfl_xor(pr, 8);
    pr += __shfl_xor(pr, 4);  pr += __shfl_xor(pr, 2);  pr += __shfl_xor(pr, 1);
    if (lane == 0) s2[wave][10] = pr;
  }
  for (int j = 0; j < 10; ++j) {
    float pr = qd * kvk[(size_t)(8 + j) * D_ + h * HD_ + tid];
    pr += __shfl_xor(pr, 32); pr += __shfl_xor(pr, 16); pr += __shfl_xor(pr, 8);
    pr += __shfl_xor(pr, 4);  pr += __shfl_xor(pr, 2);  pr += __shfl_xor(pr, 1);
    if (lane == 0) s2[wave][j] = pr;
  }
  __syncthreads();
  float s_new = (s2[0][10] + s2[1][10]) * SCALE_;
  float M2 = fmaxf(M, s_new);
  float eM = __expf(M - M2), eN = __expf(s_new - M2);
  L = L * eM + eN;
  O = O * eM + eN * kvv[qi];
  float main_out = O / L;
  float ma = -INFINITY, sa[10];
  for (int j = 0; j < 10; ++j) { sa[j] = (s2[0][j] + s2[1][j]) * SCALE_; ma = fmaxf(ma, sa[j]); }
  float la = 0.f, pj[10];
  for (int j = 0; j < 10; ++j) { pj[j] = __expf(sa[j] - ma); la += pj[j]; }
  float ao = 0.f;
  for (int j = 0; j < 10; ++j) ao += pj[j] * kvv[(size_t)(8 + j) * D_ + h * HD_ + tid];
  ao /= la;
  float g = tanhf(gate[h]);
  attn[qi] = main_out + g * ao;
}

extern "C" void kernel_launch(void* const* d_in, const int* in_sizes, int n_in,
                              void* d_out, int out_size, void* d_ws, size_t ws_size,
                              hipStream_t stream) {
  (void)in_sizes; (void)n_in; (void)out_size; (void)ws_size;
  const float* x       = (const float*)d_in[0];
  const float* adapter = (const float*)d_in[1];
  const float* ck      = (const float*)d_in[2];
  const float* cv      = (const float*)d_in[3];
  const float* fc      = (const float*)d_in[4];
  const float* fs      = (const float*)d_in[5];
  const float* wq      = (const float*)d_in[6];
  const float* wk      = (const float*)d_in[7];
  const float* wv      = (const float*)d_in[8];
  const float* wo      = (const float*)d_in[9];
  const float* gate    = (const float*)d_in[10];
  const float* anw     = (const float*)d_in[11];
  const float* fnw     = (const float*)d_in[12];
  const float* w1      = (const float*)d_in[13];
  const float* w2      = (const float*)d_in[14];
  const float* w3      = (const float*)d_in[15];
  float* out = (float*)d_out;

  float* ws      = (float*)d_ws;
  float* xa      = ws;                     // 18*4096
  float* qp      = xa + 18 * D_;           // rows 0..7 = q (roped)
  float* kp      = qp + 18 * D_;           // rows 0..7 = new k (roped), 8..17 = ak
  float* vp      = kp + 18 * D_;           // rows 0..7 = new v, 8..17 = av
  float* attn    = vp + 18 * D_;           // 8*4096
  float* hbuf    = attn + 8 * D_;          // 8*4096
  float* hn      = hbuf + 8 * D_;          // 8*4096
  float* gb      = hn + 8 * D_;            // 8*11008
  float* scratch = gb + 8 * FF_;           // live phase max: QKV partials 3*16*18*4096 = 13.5 MB
  float* dummy   = scratch + 3 * 16 * 18 * D_;  // diagnostic sink (~5.6 MB); total ws ~25 MB

  // ===================== real pipeline (identical to R11, 394.8 us) =====================
  norm_adapter_k<<<18, 256, 0, stream>>>(x, anw, adapter, xa);
  gemv_rs<18, 5, 256, 16><<<dim3(16, 16, 3), 256, 0, stream>>>(xa, wq, wk, wv, scratch, D_, D_);
  reduce3_rope_k<<<dim3(72, 1, 3), 256, 0, stream>>>(scratch, fc, fs, qp, kp, vp);
  attn_partial<<<2048, 256, 0, stream>>>(qp, ck, cv, scratch);
  attn_combine<<<256, 128, 0, stream>>>(scratch, qp, kp, vp, gate, attn);
  gemv_rs<8, 2, 128, 16><<<dim3(16, 32, 1), 256, 0, stream>>>(attn, wo, wo, wo, scratch, D_, D_);
  h_norm_k<<<8, 1024, 0, stream>>>(scratch, x, fnw, hbuf, hn, 32);
  gemv_rs<8, 2, 512, 16><<<dim3(43, 8, 2), 256, 0, stream>>>(hn, w1, w3, w3, scratch, FF_, D_);
  reduce_silu_k<<<86, 256, 0, stream>>>(scratch, gb);
  gemv_rs<8, 2, 344, 8><<<dim3(16, 32, 1), 256, 0, stream>>>(gb, w2, w2, w2, scratch, D_, FF_);
  reduceB_k<<<32, 256, 0, stream>>>(scratch, hbuf, out, 8192, 32);

  // ===================== DIAGNOSTICS (after out is complete; dummy writes) ==============
  // attn4_k: 4 sweeps of the exact attention body in one dispatch -> dur/4 = true attn time,
  // its row shows hbm_gbps/VALUBusy/Occupancy for the attention access pattern.
  attn4_k<<<8192, 256, 0, stream>>>(qp, ck, cv, dummy);
  // ffn_rep_k: 6 sweeps of the FFN gemv -> dur/6 = true FFN-gemv time.
  ffn_rep_k<8, 2, 512, 16><<<dim3(43, 48, 2), 256, 0, stream>>>(hn, w1, w3, dummy, FF_, D_);
}

// Round 14
// 405.939 us; speedup vs baseline: 2.8149x; 2.8149x over previous
//
#include <hip/hip_runtime.h>
#include <cmath>

#define D_ 4096
#define H_ 32
#define HD_ 128
#define B_ 8
#define MAXSEQ_ 2048
#define AL_ 10
#define FF_ 11008
#define SCALE_ 0.08838834764831845f   // 1/sqrt(128)
#define EPS_ 1e-5f
#define PSTRIDE 160                   // attn partial record stride (floats); o[] at +32 (64B aligned)
#define QKV_CS (18 * D_)              // QKV partial chunk stride (73728 floats)
#define QKV_ZS (16 * 18 * D_)         // QKV partial z stride (1179648 floats)

// ---------- fused: rmsnorm(x) -> xa rows 0..7 ; adapter copy -> xa rows 8..17 ----------
__global__ __launch_bounds__(256) void norm_adapter_k(const float* __restrict__ x,
                                                      const float* __restrict__ w,
                                                      const float* __restrict__ adapter,
                                                      float* __restrict__ xa) {
  int b = blockIdx.x, tid = threadIdx.x;
  if (b < 8) {
    const float* xr = x + (size_t)b * D_;
    float ss = 0.f;
    for (int i = tid; i < D_; i += 256) { float v = xr[i]; ss += v * v; }
    __shared__ float red[256];
    red[tid] = ss; __syncthreads();
    for (int s = 128; s; s >>= 1) { if (tid < s) red[tid] += red[tid + s]; __syncthreads(); }
    float r = rsqrtf(red[0] / (float)D_ + EPS_);
    float* o = xa + (size_t)b * D_;
    for (int i = tid; i < D_; i += 256) o[i] = xr[i] * r * w[i];
  } else {
    int r = b - 8;
    const float4* src = (const float4*)(adapter + (size_t)r * D_);
    float4* dst = (float4*)(xa + (size_t)(8 + r) * D_);
    for (int i = tid; i < D_ / 4; i += 256) dst[i] = src[i];
  }
}

// ------------- row-split split-K GEMV: 4 waves/block, each wave owns <=NR rows -------------
template<int NR, int ROWS, int CHUNK, int UNROLL>
__device__ __forceinline__ void gemv_core(
    const float4* __restrict__ W4, const float (*xs)[ROWS],
    int i0, int N4, int j4, int r0, float* __restrict__ P, size_t pb, int N) {
  float4 acc[NR];
#pragma unroll
  for (int r = 0; r < NR; ++r) acc[r] = make_float4(0.f, 0.f, 0.f, 0.f);
  for (int iu = 0; iu < CHUNK; iu += UNROLL) {
    float4 w[UNROLL];
#pragma unroll
    for (int u = 0; u < UNROLL; ++u)
      w[u] = W4[(size_t)(i0 + iu + u) * N4 + j4];
#pragma unroll
    for (int u = 0; u < UNROLL; ++u) {
#pragma unroll
      for (int r = 0; r < NR; ++r) {
        float xv = xs[iu + u][r0 + r];
        acc[r].x += xv * w[u].x; acc[r].y += xv * w[u].y;
        acc[r].z += xv * w[u].z; acc[r].w += xv * w[u].w;
      }
    }
  }
#pragma unroll
  for (int r = 0; r < NR; ++r)
    *(float4*)&P[(pb + r) * (size_t)N + (size_t)4 * j4] = acc[r];
}

// grid = (N4/64, K/CHUNK, nmat); block = 256 (4 waves).
template<int ROWS, int RPG, int CHUNK, int UNROLL>
__global__ __launch_bounds__(256, 1) void gemv_rs(
    const float* __restrict__ X,
    const float* __restrict__ Wa, const float* __restrict__ Wb, const float* __restrict__ Wc,
    float* __restrict__ P, int N, int K) {
  const float* W = (blockIdx.z == 0) ? Wa : (blockIdx.z == 1) ? Wb : Wc;
  __shared__ float xs[CHUNK][ROWS];
  int tid = threadIdx.x;
  int i0 = blockIdx.y * CHUNK;
  for (int idx = tid; idx < ROWS * CHUNK; idx += 256) {
    int r = idx / CHUNK, ii = idx - r * CHUNK;
    xs[ii][r] = X[(size_t)r * K + i0 + ii];
  }
  __syncthreads();
  int wave = tid >> 6, lane = tid & 63;
  int r0 = wave * RPG;
  int N4 = N >> 2;
  int j4 = blockIdx.x * 64 + lane;
  const float4* W4 = (const float4*)W;
  size_t pb = ((size_t)blockIdx.z * gridDim.y + blockIdx.y) * ROWS + r0;
  constexpr int LAST = ROWS - 3 * RPG;
  if (r0 + RPG <= ROWS)
    gemv_core<RPG, ROWS, CHUNK, UNROLL>(W4, xs, i0, N4, j4, r0, P, pb, N);
  else if (LAST > 0)
    gemv_core<(LAST > 0 ? LAST : 1), ROWS, CHUNK, UNROLL>(W4, xs, i0, N4, j4, r0, P, pb, N);
}

// ------- reduction with residual base: Y = base + sum_c P[c] -------
__global__ __launch_bounds__(256) void reduceB_k(const float* __restrict__ P,
                                                 const float* __restrict__ base,
                                                 float* __restrict__ Y, int n4, int nc) {
  int i4 = blockIdx.x * 256 + threadIdx.x;
  if (i4 >= n4) return;
  const float4* P4 = (const float4*)P;
  float4 s = ((const float4*)base)[i4];
  for (int c = 0; c < nc; ++c) {
    float4 v = P4[(size_t)c * n4 + i4];
    s.x += v.x; s.y += v.y; s.z += v.z; s.w += v.w;
  }
  ((float4*)Y)[i4] = s;
}

// ------- fused: h = x + sum_c P[c] (wo partials) ; hn = rmsnorm(h) -------
// grid = 8 (one per b), block = 1024; P layout [chunk nc][8][4096]
__global__ __launch_bounds__(1024) void h_norm_k(const float* __restrict__ P,
                                                 const float* __restrict__ x,
                                                 const float* __restrict__ w,
                                                 float* __restrict__ hbuf,
                                                 float* __restrict__ hn, int nc) {
  int b = blockIdx.x, tid = threadIdx.x;        // tid = float4 index in row
  const float4* P4 = (const float4*)P;
  float4 s = ((const float4*)x)[b * 1024 + tid];
  for (int c = 0; c < nc; ++c) {
    float4 v = P4[((size_t)c * 8 + b) * 1024 + tid];
    s.x += v.x; s.y += v.y; s.z += v.z; s.w += v.w;
  }
  ((float4*)hbuf)[b * 1024 + tid] = s;
  float ss = s.x * s.x + s.y * s.y + s.z * s.z + s.w * s.w;
  __shared__ float red[1024];
  red[tid] = ss; __syncthreads();
  for (int st = 512; st; st >>= 1) { if (tid < st) red[tid] += red[tid + st]; __syncthreads(); }
  float r = rsqrtf(red[0] / (float)D_ + EPS_);
  float4 wv = ((const float4*)w)[tid];
  float4 o;
  o.x = s.x * r * wv.x; o.y = s.y * r * wv.y; o.z = s.z * r * wv.z; o.w = s.w * r * wv.w;
  ((float4*)hn)[b * 1024 + tid] = o;
}

// ------- FFN: gb = silu(sum P[z=0]) * (sum P[z=1]) ; P [z(2)][chunk(8)][8][11008] -------
__global__ __launch_bounds__(256) void reduce_silu_k(const float* __restrict__ P,
                                                     float* __restrict__ gb) {
  int i4 = blockIdx.x * 256 + threadIdx.x;      // < 22016
  const float4* P4 = (const float4*)P;
  float4 a = make_float4(0.f, 0.f, 0.f, 0.f);
  float4 b = make_float4(0.f, 0.f, 0.f, 0.f);
#pragma unroll
  for (int c = 0; c < 8; ++c) {
    float4 u = P4[(size_t)c * 22016 + i4];
    float4 v = P4[(size_t)(8 + c) * 22016 + i4];
    a.x += u.x; a.y += u.y; a.z += u.z; a.w += u.w;
    b.x += v.x; b.y += v.y; b.z += v.z; b.w += v.w;
  }
  float4 o;
  o.x = (a.x / (1.f + __expf(-a.x))) * b.x;
  o.y = (a.y / (1.f + __expf(-a.y))) * b.y;
  o.z = (a.z / (1.f + __expf(-a.z))) * b.z;
  o.w = (a.w / (1.f + __expf(-a.w))) * b.w;
  ((float4*)gb)[i4] = o;
}

// --------- attention pass 1: q-row built inline from QKV partials (+rope), then
// barrier-free online flash-decode over the cache. One (b,h,chunk-of-256) per block. ---------
__global__ __launch_bounds__(256) void attn_partial(
    const float* __restrict__ P,    // QKV partials [z][16][18][4096]
    const float* __restrict__ fc, const float* __restrict__ fs,
    const float* __restrict__ ck,
    const float* __restrict__ cv,
    float* __restrict__ part) {
  int idx = blockIdx.x;
  int c = idx & 7, bh = idx >> 3;
  int h = bh & 31, b = bh >> 5;
  int tid = threadIdx.x, wave = tid >> 6, lane = tid & 63;
  int half = lane >> 5, l32 = lane & 31;
  __shared__ float qraw[128];
  __shared__ float qs[128];
  // ---- stage roped q-row (z=0, row b) from 16 chunk partials ----
  if (tid < 128) {
    size_t base = (size_t)b * D_ + h * HD_ + tid;
    float s = 0.f;
#pragma unroll
    for (int c2 = 0; c2 < 16; ++c2) s += P[base + (size_t)c2 * QKV_CS];
    qraw[tid] = s;
  }
  __syncthreads();
  if (tid < 128) {
    int p0 = tid >> 1;
    float v = (tid & 1) ? (qraw[tid ^ 1] * fs[p0] + qraw[tid] * fc[p0])
                        : (qraw[tid] * fc[p0] - qraw[tid ^ 1] * fs[p0]);
    qs[tid] = v;
  }
  __syncthreads();
  const float4 qv = *(const float4*)&qs[4 * l32];
  int t0 = c * 256 + wave * 64;
  const size_t kvbase = ((size_t)b * MAXSEQ_) * (H_ * HD_) + (size_t)h * HD_ + 4 * l32;
  float m = -INFINITY, l = 0.f;
  float4 o = make_float4(0.f, 0.f, 0.f, 0.f);
#pragma unroll 4
  for (int i = 0; i < 32; ++i) {
    int t = t0 + 2 * i + half;
    size_t off = kvbase + (size_t)t * (H_ * HD_);
    float4 kv = *(const float4*)&ck[off];
    float s = qv.x * kv.x + qv.y * kv.y + qv.z * kv.z + qv.w * kv.w;
    s += __shfl_xor(s, 16); s += __shfl_xor(s, 8);
    s += __shfl_xor(s, 4);  s += __shfl_xor(s, 2); s += __shfl_xor(s, 1);
    s *= SCALE_;
    if (t == MAXSEQ_ - 1) s = -1e30f;     // new token folded in combine
    float mn = fmaxf(m, s);
    float r = __expf(m - mn), p = __expf(s - mn);
    float4 vv = *(const float4*)&cv[off];
    o.x = o.x * r + p * vv.x; o.y = o.y * r + p * vv.y;
    o.z = o.z * r + p * vv.z; o.w = o.w * r + p * vv.w;
    l = l * r + p; m = mn;
  }
  // merge the two 32-lane halves
  float mo = __shfl_xor(m, 32);
  float M = fmaxf(m, mo);
  float e = __expf(m - M);
  o.x *= e; o.y *= e; o.z *= e; o.w *= e; l *= e;
  o.x += __shfl_xor(o.x, 32); o.y += __shfl_xor(o.y, 32);
  o.z += __shfl_xor(o.z, 32); o.w += __shfl_xor(o.w, 32);
  l += __shfl_xor(l, 32);
  float* po = &part[((size_t)idx * 4 + wave) * PSTRIDE];
  if (lane == 0) { po[0] = M; po[1] = l; }
  if (half == 0) *(float4*)&po[32 + 4 * l32] = o;
}

// --- attention pass 2: combine 32 partials; q/k/v/adapter rows reduced inline from
// QKV partials (k roped via LDS pair-exchange); new token + adapter attention + gate. ---
__global__ __launch_bounds__(128) void attn_combine(
    const float* __restrict__ part,
    const float* __restrict__ P,    // QKV partials [z][16][18][4096]
    const float* __restrict__ fc, const float* __restrict__ fs,
    const float* __restrict__ gate,
    float* __restrict__ attn) {
  int bh = blockIdx.x;
  int h = bh & 31, b = bh >> 5;
  int tid = threadIdx.x;            // = d in [0,128)
  int wave = tid >> 6, lane = tid & 63;
  const float* pb = &part[(size_t)bh * 32 * PSTRIDE];
  __shared__ float sm[32], sl[32];
  __shared__ float s2[2][12];
  __shared__ float qraw[128], kraw[128];
  // ---- inline reductions of q (roped), k_new (roped), v_new ----
  size_t ebase = (size_t)b * D_ + h * HD_ + tid;  // row b, element d=tid
  float qsum = 0.f, ksum = 0.f, vsum = 0.f;
#pragma unroll
  for (int c2 = 0; c2 < 16; ++c2) {
    size_t off = ebase + (size_t)c2 * QKV_CS;
    qsum += P[off];
    ksum += P[off + QKV_ZS];
    vsum += P[off + 2 * (size_t)QKV_ZS];
  }
  qraw[tid] = qsum; kraw[tid] = ksum;
  if (tid < 32) { sm[tid] = pb[tid * PSTRIDE]; sl[tid] = pb[tid * PSTRIDE + 1]; }
  __syncthreads();
  int p0 = tid >> 1;
  float qd, knd;
  if (tid & 1) {
    qd  = qraw[tid ^ 1] * fs[p0] + qraw[tid] * fc[p0];
    knd = kraw[tid ^ 1] * fs[p0] + kraw[tid] * fc[p0];
  } else {
    qd  = qraw[tid] * fc[p0] - qraw[tid ^ 1] * fs[p0];
    knd = kraw[tid] * fc[p0] - kraw[tid ^ 1] * fs[p0];
  }
  // ---- combine the 32 cache partials ----
  float M = -INFINITY;
  for (int c = 0; c < 32; ++c) M = fmaxf(M, sm[c]);
  float L = 0.f, O = 0.f;
#pragma unroll 4
  for (int c = 0; c < 32; ++c) {
    float e = __expf(sm[c] - M);
    L += e * sl[c];
    O += e * pb[c * PSTRIDE + 32 + tid];
  }
  // ---- shuffle-based scores: new token (idx 10) + 10 adapter keys (rows 8..17 of z=1) ----
  {
    float pr = qd * knd;
    pr += __shfl_xor(pr, 32); pr += __shfl_xor(pr, 16); pr += __shfl_xor(pr, 8);
    pr += __shfl_xor(pr, 4);  pr += __shfl_xor(pr, 2);  pr += __shfl_xor(pr, 1);
    if (lane == 0) s2[wave][10] = pr;
  }
  for (int j = 0; j < 10; ++j) {
    size_t abase = (size_t)(8 + j) * D_ + h * HD_ + tid + QKV_ZS;
    float aksum = 0.f;
#pragma unroll
    for (int c2 = 0; c2 < 16; ++c2) aksum += P[abase + (size_t)c2 * QKV_CS];
    float pr = qd * aksum;
    pr += __shfl_xor(pr, 32); pr += __shfl_xor(pr, 16); pr += __shfl_xor(pr, 8);
    pr += __shfl_xor(pr, 4);  pr += __shfl_xor(pr, 2);  pr += __shfl_xor(pr, 1);
    if (lane == 0) s2[wave][j] = pr;
  }
  __syncthreads();
  float s_new = (s2[0][10] + s2[1][10]) * SCALE_;
  float M2 = fmaxf(M, s_new);
  float eM = __expf(M - M2), eN = __expf(s_new - M2);
  L = L * eM + eN;
  O = O * eM + eN * vsum;
  float main_out = O / L;
  float ma = -INFINITY, sa[10];
  for (int j = 0; j < 10; ++j) { sa[j] = (s2[0][j] + s2[1][j]) * SCALE_; ma = fmaxf(ma, sa[j]); }
  float la = 0.f, pj[10];
  for (int j = 0; j < 10; ++j) { pj[j] = __expf(sa[j] - ma); la += pj[j]; }
  float ao = 0.f;
  for (int j = 0; j < 10; ++j) {
    size_t abase = (size_t)(8 + j) * D_ + h * HD_ + tid + 2 * (size_t)QKV_ZS;
    float avsum = 0.f;
#pragma unroll
    for (int c2 = 0; c2 < 16; ++c2) avsum += P[abase + (size_t)c2 * QKV_CS];
    ao += pj[j] * avsum;
  }
  ao /= la;
  float g = tanhf(gate[h]);
  attn[ebase] = main_out + g * ao;
}

extern "C" void kernel_launch(void* const* d_in, const int* in_sizes, int n_in,
                              void* d_out, int out_size, void* d_ws, size_t ws_size,
                              hipStream_t stream) {
  (void)in_sizes; (void)n_in; (void)out_size; (void)ws_size;
  const float* x       = (const float*)d_in[0];
  const float* adapter = (const float*)d_in[1];
  const float* ck      = (const float*)d_in[2];
  const float* cv      = (const float*)d_in[3];
  const float* fc      = (const float*)d_in[4];
  const float* fs      = (const float*)d_in[5];
  const float* wq      = (const float*)d_in[6];
  const float* wk      = (const float*)d_in[7];
  const float* wv      = (const float*)d_in[8];
  const float* wo      = (const float*)d_in[9];
  const float* gate    = (const float*)d_in[10];
  const float* anw     = (const float*)d_in[11];
  const float* fnw     = (const float*)d_in[12];
  const float* w1      = (const float*)d_in[13];
  const float* w2      = (const float*)d_in[14];
  const float* w3      = (const float*)d_in[15];
  float* out = (float*)d_out;

  float* ws      = (float*)d_ws;
  float* xa      = ws;                     // 18*4096
  float* attn    = xa + 18 * D_;           // 8*4096
  float* hbuf    = attn + 8 * D_;          // 8*4096
  float* hn      = hbuf + 8 * D_;          // 8*4096
  float* gb      = hn + 8 * D_;            // 8*11008
  float* scratch = gb + 8 * FF_;           // QKV partials: 3*16*18*4096 = 3,538,944 floats
  float* apart   = scratch + 3 * QKV_ZS;   // attn partials: 8192*160 = 1,310,720 floats
  // total ws ~ 5.11 M floats (20.5 MB); wo/FFN/w2 partials reuse `scratch` after combine.

  // 1) xa = [rmsnorm(x); adapter]
  norm_adapter_k<<<18, 256, 0, stream>>>(x, anw, adapter, xa);
  // 2) QKV projections -> partials (kept; consumed directly by attention)
  gemv_rs<18, 5, 256, 16><<<dim3(16, 16, 3), 256, 0, stream>>>(xa, wq, wk, wv, scratch, D_, D_);
  // 3) flash-decode: q built inline (+rope); combine reduces k/v/adapter rows inline
  attn_partial<<<2048, 256, 0, stream>>>(scratch, fc, fs, ck, cv, apart);
  attn_combine<<<256, 128, 0, stream>>>(apart, scratch, fc, fs, gate, attn);
  // 4) h = x + attn @ wo ; hn = rmsnorm(h)  (fused reduce+norm)
  gemv_rs<8, 2, 128, 16><<<dim3(16, 32, 1), 256, 0, stream>>>(attn, wo, wo, wo, scratch, D_, D_);
  h_norm_k<<<8, 1024, 0, stream>>>(scratch, x, fnw, hbuf, hn, 32);
  // 5) FFN up+gate -> fused reduce+silu
  gemv_rs<8, 2, 512, 16><<<dim3(43, 8, 2), 256, 0, stream>>>(hn, w1, w3, w3, scratch, FF_, D_);
  reduce_silu_k<<<86, 256, 0, stream>>>(scratch, gb);
  // 6) out = h + gb @ w2
  gemv_rs<8, 2, 344, 8><<<dim3(16, 32, 1), 256, 0, stream>>>(gb, w2, w2, w2, scratch, D_, FF_);
  reduceB_k<<<32, 256, 0, stream>>>(scratch, hbuf, out, 8192, 32);
}

// Round 15
// 392.788 us; speedup vs baseline: 2.9092x; 1.0335x over previous
//
#include <hip/hip_runtime.h>
#include <cmath>

#define D_ 4096
#define H_ 32
#define HD_ 128
#define B_ 8
#define MAXSEQ_ 2048
#define AL_ 10
#define FF_ 11008
#define SCALE_ 0.08838834764831845f   // 1/sqrt(128)
#define EPS_ 1e-5f
#define PSTRIDE 160                   // attn partial record stride (floats); o[] at +32 (64B aligned)

// ---------- fused: rmsnorm(x) -> xa rows 0..7 ; adapter copy -> xa rows 8..17 ----------
__global__ __launch_bounds__(256) void norm_adapter_k(const float* __restrict__ x,
                                                      const float* __restrict__ w,
                                                      const float* __restrict__ adapter,
                                                      float* __restrict__ xa) {
  int b = blockIdx.x, tid = threadIdx.x;
  if (b < 8) {
    const float* xr = x + (size_t)b * D_;
    float ss = 0.f;
    for (int i = tid; i < D_; i += 256) { float v = xr[i]; ss += v * v; }
    __shared__ float red[256];
    red[tid] = ss; __syncthreads();
    for (int s = 128; s; s >>= 1) { if (tid < s) red[tid] += red[tid + s]; __syncthreads(); }
    float r = rsqrtf(red[0] / (float)D_ + EPS_);
    float* o = xa + (size_t)b * D_;
    for (int i = tid; i < D_; i += 256) o[i] = xr[i] * r * w[i];
  } else {
    int r = b - 8;
    const float4* src = (const float4*)(adapter + (size_t)r * D_);
    float4* dst = (float4*)(xa + (size_t)(8 + r) * D_);
    for (int i = tid; i < D_ / 4; i += 256) dst[i] = src[i];
  }
}

// ------------- row-split split-K GEMV: 4 waves/block, each wave owns <=NR rows -------------
template<int NR, int ROWS, int CHUNK, int UNROLL>
__device__ __forceinline__ void gemv_core(
    const float4* __restrict__ W4, const float (*xs)[ROWS],
    int i0, int N4, int j4, int r0, float* __restrict__ P, size_t pb, int N) {
  float4 acc[NR];
#pragma unroll
  for (int r = 0; r < NR; ++r) acc[r] = make_float4(0.f, 0.f, 0.f, 0.f);
  for (int iu = 0; iu < CHUNK; iu += UNROLL) {
    float4 w[UNROLL];
#pragma unroll
    for (int u = 0; u < UNROLL; ++u)
      w[u] = W4[(size_t)(i0 + iu + u) * N4 + j4];
#pragma unroll
    for (int u = 0; u < UNROLL; ++u) {
#pragma unroll
      for (int r = 0; r < NR; ++r) {
        float xv = xs[iu + u][r0 + r];
        acc[r].x += xv * w[u].x; acc[r].y += xv * w[u].y;
        acc[r].z += xv * w[u].z; acc[r].w += xv * w[u].w;
      }
    }
  }
#pragma unroll
  for (int r = 0; r < NR; ++r)
    *(float4*)&P[(pb + r) * (size_t)N + (size_t)4 * j4] = acc[r];
}

// grid = (N4/64, K/CHUNK, nmat); block = 256 (4 waves).
template<int ROWS, int RPG, int CHUNK, int UNROLL>
__global__ __launch_bounds__(256, 1) void gemv_rs(
    const float* __restrict__ X,
    const float* __restrict__ Wa, const float* __restrict__ Wb, const float* __restrict__ Wc,
    float* __restrict__ P, int N, int K) {
  const float* W = (blockIdx.z == 0) ? Wa : (blockIdx.z == 1) ? Wb : Wc;
  __shared__ float xs[CHUNK][ROWS];
  int tid = threadIdx.x;
  int i0 = blockIdx.y * CHUNK;
  for (int idx = tid; idx < ROWS * CHUNK; idx += 256) {
    int r = idx / CHUNK, ii = idx - r * CHUNK;
    xs[ii][r] = X[(size_t)r * K + i0 + ii];
  }
  __syncthreads();
  int wave = tid >> 6, lane = tid & 63;
  int r0 = wave * RPG;
  int N4 = N >> 2;
  int j4 = blockIdx.x * 64 + lane;
  const float4* W4 = (const float4*)W;
  size_t pb = ((size_t)blockIdx.z * gridDim.y + blockIdx.y) * ROWS + r0;
  constexpr int LAST = ROWS - 3 * RPG;
  if (r0 + RPG <= ROWS)
    gemv_core<RPG, ROWS, CHUNK, UNROLL>(W4, xs, i0, N4, j4, r0, P, pb, N);
  else if (LAST > 0)
    gemv_core<(LAST > 0 ? LAST : 1), ROWS, CHUNK, UNROLL>(W4, xs, i0, N4, j4, r0, P, pb, N);
}

// ------- QKV reduction over 16 chunks + fused RoPE on q,k rows 0..7 -------
// P: [z(3)][chunk(16)][row(18)][4096]
__global__ __launch_bounds__(256) void reduce3_rope_k(
    const float* __restrict__ P, const float* __restrict__ fc, const float* __restrict__ fs,
    float* __restrict__ Ya, float* __restrict__ Yb, float* __restrict__ Yc) {
  int z = blockIdx.z;
  int i4 = blockIdx.x * 256 + threadIdx.x;      // 18432 float4 per z
  const float4* P4 = (const float4*)P;
  size_t base = (size_t)z * 16 * 18432 + i4;
  float4 s = make_float4(0.f, 0.f, 0.f, 0.f);
#pragma unroll
  for (int c = 0; c < 16; ++c) {
    float4 v = P4[base + (size_t)c * 18432];
    s.x += v.x; s.y += v.y; s.z += v.z; s.w += v.w;
  }
  int row = i4 >> 10;
  if (z < 2 && row < 8) {
    int c0 = (i4 & 1023) << 2;
    int p0 = (c0 & 127) >> 1;
    float ca = fc[p0], sa = fs[p0], cb = fc[p0 + 1], sb = fs[p0 + 1];
    float4 r;
    r.x = s.x * ca - s.y * sa; r.y = s.x * sa + s.y * ca;
    r.z = s.z * cb - s.w * sb; r.w = s.z * sb + s.w * cb;
    s = r;
  }
  float4* Y = (float4*)(z == 0 ? Ya : z == 1 ? Yb : Yc);
  Y[i4] = s;
}

// ------- reduction with residual base: Y = base + sum_c P[c] -------
__global__ __launch_bounds__(256) void reduceB_k(const float* __restrict__ P,
                                                 const float* __restrict__ base,
                                                 float* __restrict__ Y, int n4, int nc) {
  int i4 = blockIdx.x * 256 + threadIdx.x;
  if (i4 >= n4) return;
  const float4* P4 = (const float4*)P;
  float4 s = ((const float4*)base)[i4];
  for (int c = 0; c < nc; ++c) {
    float4 v = P4[(size_t)c * n4 + i4];
    s.x += v.x; s.y += v.y; s.z += v.z; s.w += v.w;
  }
  ((float4*)Y)[i4] = s;
}

// ------- fused: h = x + sum_c P[c] (wo partials) ; hn = rmsnorm(h) -------
// grid = 8 (one per b), block = 1024; P layout [chunk nc][8][4096]
__global__ __launch_bounds__(1024) void h_norm_k(const float* __restrict__ P,
                                                 const float* __restrict__ x,
                                                 const float* __restrict__ w,
                                                 float* __restrict__ hbuf,
                                                 float* __restrict__ hn, int nc) {
  int b = blockIdx.x, tid = threadIdx.x;        // tid = float4 index in row
  const float4* P4 = (const float4*)P;
  float4 s = ((const float4*)x)[b * 1024 + tid];
  for (int c = 0; c < nc; ++c) {
    float4 v = P4[((size_t)c * 8 + b) * 1024 + tid];
    s.x += v.x; s.y += v.y; s.z += v.z; s.w += v.w;
  }
  ((float4*)hbuf)[b * 1024 + tid] = s;
  float ss = s.x * s.x + s.y * s.y + s.z * s.z + s.w * s.w;
  __shared__ float red[1024];
  red[tid] = ss; __syncthreads();
  for (int st = 512; st; st >>= 1) { if (tid < st) red[tid] += red[tid + st]; __syncthreads(); }
  float r = rsqrtf(red[0] / (float)D_ + EPS_);
  float4 wv = ((const float4*)w)[tid];
  float4 o;
  o.x = s.x * r * wv.x; o.y = s.y * r * wv.y; o.z = s.z * r * wv.z; o.w = s.w * r * wv.w;
  ((float4*)hn)[b * 1024 + tid] = o;
}

// ------- FFN: gb = silu(sum P[z=0]) * (sum P[z=1]) ; P [z(2)][chunk(8)][8][11008] -------
__global__ __launch_bounds__(256) void reduce_silu_k(const float* __restrict__ P,
                                                     float* __restrict__ gb) {
  int i4 = blockIdx.x * 256 + threadIdx.x;      // < 22016
  const float4* P4 = (const float4*)P;
  float4 a = make_float4(0.f, 0.f, 0.f, 0.f);
  float4 b = make_float4(0.f, 0.f, 0.f, 0.f);
#pragma unroll
  for (int c = 0; c < 8; ++c) {
    float4 u = P4[(size_t)c * 22016 + i4];
    float4 v = P4[(size_t)(8 + c) * 22016 + i4];
    a.x += u.x; a.y += u.y; a.z += u.z; a.w += u.w;
    b.x += v.x; b.y += v.y; b.z += v.z; b.w += v.w;
  }
  float4 o;
  o.x = (a.x / (1.f + __expf(-a.x))) * b.x;
  o.y = (a.y / (1.f + __expf(-a.y))) * b.y;
  o.z = (a.z / (1.f + __expf(-a.z))) * b.z;
  o.w = (a.w / (1.f + __expf(-a.w))) * b.w;
  ((float4*)gb)[i4] = o;
}

// ---------------- attention pass 1: barrier-free online flash-decode ----------------
__global__ __launch_bounds__(256) void attn_partial(
    const float* __restrict__ qp,   // rows 0..7 = q, post-rope
    const float* __restrict__ ck,
    const float* __restrict__ cv,
    float* __restrict__ part) {
  int idx = blockIdx.x;
  int c = idx & 7, bh = idx >> 3;
  int h = bh & 31, b = bh >> 5;
  int tid = threadIdx.x, wave = tid >> 6, lane = tid & 63;
  int half = lane >> 5, l32 = lane & 31;
  int t0 = c * 256 + wave * 64;
  const float4 qv = *(const float4*)&qp[(size_t)b * D_ + h * HD_ + 4 * l32];
  const size_t kvbase = ((size_t)b * MAXSEQ_) * (H_ * HD_) + (size_t)h * HD_ + 4 * l32;
  float m = -INFINITY, l = 0.f;
  float4 o = make_float4(0.f, 0.f, 0.f, 0.f);
#pragma unroll 4
  for (int i = 0; i < 32; ++i) {
    int t = t0 + 2 * i + half;
    size_t off = kvbase + (size_t)t * (H_ * HD_);
    float4 kv = *(const float4*)&ck[off];
    float s = qv.x * kv.x + qv.y * kv.y + qv.z * kv.z + qv.w * kv.w;
    s += __shfl_xor(s, 16); s += __shfl_xor(s, 8);
    s += __shfl_xor(s, 4);  s += __shfl_xor(s, 2); s += __shfl_xor(s, 1);
    s *= SCALE_;
    if (t == MAXSEQ_ - 1) s = -1e30f;     // new token folded in combine
    float mn = fmaxf(m, s);
    float r = __expf(m - mn), p = __expf(s - mn);
    float4 vv = *(const float4*)&cv[off];
    o.x = o.x * r + p * vv.x; o.y = o.y * r + p * vv.y;
    o.z = o.z * r + p * vv.z; o.w = o.w * r + p * vv.w;
    l = l * r + p; m = mn;
  }
  // merge the two 32-lane halves
  float mo = __shfl_xor(m, 32);
  float M = fmaxf(m, mo);
  float e = __expf(m - M);
  o.x *= e; o.y *= e; o.z *= e; o.w *= e; l *= e;
  o.x += __shfl_xor(o.x, 32); o.y += __shfl_xor(o.y, 32);
  o.z += __shfl_xor(o.z, 32); o.w += __shfl_xor(o.w, 32);
  l += __shfl_xor(l, 32);
  float* po = &part[((size_t)idx * 4 + wave) * PSTRIDE];
  if (lane == 0) { po[0] = M; po[1] = l; }
  if (half == 0) *(float4*)&po[32 + 4 * l32] = o;
}

// --- attention pass 2 (shuffle-based): combine 32 partials + new token + adapter + gate ---
__global__ __launch_bounds__(128) void attn_combine(
    const float* __restrict__ part,
    const float* __restrict__ qp,
    const float* __restrict__ kvk,  // rows 0..7 = new k (roped), rows 8..17 = ak
    const float* __restrict__ kvv,  // rows 0..7 = new v,         rows 8..17 = av
    const float* __restrict__ gate,
    float* __restrict__ attn) {
  int bh = blockIdx.x;
  int h = bh & 31, b = bh >> 5;
  int tid = threadIdx.x;            // = d in [0,128)
  int wave = tid >> 6, lane = tid & 63;
  const float* pb = &part[(size_t)bh * 32 * PSTRIDE];
  __shared__ float sm[32], sl[32];
  __shared__ float s2[2][12];
  if (tid < 32) { sm[tid] = pb[tid * PSTRIDE]; sl[tid] = pb[tid * PSTRIDE + 1]; }
  __syncthreads();
  float M = -INFINITY;
  for (int c = 0; c < 32; ++c) M = fmaxf(M, sm[c]);
  float L = 0.f, O = 0.f;
#pragma unroll 4
  for (int c = 0; c < 32; ++c) {
    float e = __expf(sm[c] - M);
    L += e * sl[c];
    O += e * pb[c * PSTRIDE + 32 + tid];
  }
  // shuffle-based scores: new token (idx 10) + 10 adapter keys
  size_t qi = (size_t)b * D_ + h * HD_ + tid;
  float qd = qp[qi];
  {
    float pr = qd * kvk[qi];
    pr += __shfl_xor(pr, 32); pr += __shfl_xor(pr, 16); pr += __shfl_xor(pr, 8);
    pr += __shfl_xor(pr, 4);  pr += __shfl_xor(pr, 2);  pr += __shfl_xor(pr, 1);
    if (lane == 0) s2[wave][10] = pr;
  }
  for (int j = 0; j < 10; ++j) {
    float pr = qd * kvk[(size_t)(8 + j) * D_ + h * HD_ + tid];
    pr += __shfl_xor(pr, 32); pr += __shfl_xor(pr, 16); pr += __shfl_xor(pr, 8);
    pr += __shfl_xor(pr, 4);  pr += __shfl_xor(pr, 2);  pr += __shfl_xor(pr, 1);
    if (lane == 0) s2[wave][j] = pr;
  }
  __syncthreads();
  float s_new = (s2[0][10] + s2[1][10]) * SCALE_;
  float M2 = fmaxf(M, s_new);
  float eM = __expf(M - M2), eN = __expf(s_new - M2);
  L = L * eM + eN;
  O = O * eM + eN * kvv[qi];
  float main_out = O / L;
  float ma = -INFINITY, sa[10];
  for (int j = 0; j < 10; ++j) { sa[j] = (s2[0][j] + s2[1][j]) * SCALE_; ma = fmaxf(ma, sa[j]); }
  float la = 0.f, pj[10];
  for (int j = 0; j < 10; ++j) { pj[j] = __expf(sa[j] - ma); la += pj[j]; }
  float ao = 0.f;
  for (int j = 0; j < 10; ++j) ao += pj[j] * kvv[(size_t)(8 + j) * D_ + h * HD_ + tid];
  ao /= la;
  float g = tanhf(gate[h]);
  attn[qi] = main_out + g * ao;
}

extern "C" void kernel_launch(void* const* d_in, const int* in_sizes, int n_in,
                              void* d_out, int out_size, void* d_ws, size_t ws_size,
                              hipStream_t stream) {
  (void)in_sizes; (void)n_in; (void)out_size; (void)ws_size;
  const float* x       = (const float*)d_in[0];
  const float* adapter = (const float*)d_in[1];
  const float* ck      = (const float*)d_in[2];
  const float* cv      = (const float*)d_in[3];
  const float* fc      = (const float*)d_in[4];
  const float* fs      = (const float*)d_in[5];
  const float* wq      = (const float*)d_in[6];
  const float* wk      = (const float*)d_in[7];
  const float* wv      = (const float*)d_in[8];
  const float* wo      = (const float*)d_in[9];
  const float* gate    = (const float*)d_in[10];
  const float* anw     = (const float*)d_in[11];
  const float* fnw     = (const float*)d_in[12];
  const float* w1      = (const float*)d_in[13];
  const float* w2      = (const float*)d_in[14];
  const float* w3      = (const float*)d_in[15];
  float* out = (float*)d_out;

  float* ws      = (float*)d_ws;
  float* xa      = ws;                     // 18*4096
  float* qp      = xa + 18 * D_;           // rows 0..7 = q (roped)
  float* kp      = qp + 18 * D_;           // rows 0..7 = new k (roped), 8..17 = ak
  float* vp      = kp + 18 * D_;           // rows 0..7 = new v, 8..17 = av
  float* attn    = vp + 18 * D_;           // 8*4096
  float* hbuf    = attn + 8 * D_;          // 8*4096
  float* hn      = hbuf + 8 * D_;          // 8*4096
  float* gb      = hn + 8 * D_;            // 8*11008
  float* scratch = gb + 8 * FF_;           // max phase: QKV partials 3*16*18*4096 = 13.5 MB

  // 1) xa = [rmsnorm(x); adapter]
  norm_adapter_k<<<18, 256, 0, stream>>>(x, anw, adapter, xa);
  // 2) QKV projections -> partials -> reduce (+rope q,k rows 0..7)
  gemv_rs<18, 5, 256, 16><<<dim3(16, 16, 3), 256, 0, stream>>>(xa, wq, wk, wv, scratch, D_, D_);
  reduce3_rope_k<<<dim3(72, 1, 3), 256, 0, stream>>>(scratch, fc, fs, qp, kp, vp);
  // 3) barrier-free flash-decode (new token folded in combine)
  attn_partial<<<2048, 256, 0, stream>>>(qp, ck, cv, scratch);
  attn_combine<<<256, 128, 0, stream>>>(scratch, qp, kp, vp, gate, attn);
  // 4) h = x + attn @ wo ; hn = rmsnorm(h)  (fused reduce+norm)
  gemv_rs<8, 2, 128, 16><<<dim3(16, 32, 1), 256, 0, stream>>>(attn, wo, wo, wo, scratch, D_, D_);
  h_norm_k<<<8, 1024, 0, stream>>>(scratch, x, fnw, hbuf, hn, 32);
  // 5) FFN up+gate -> fused reduce+silu
  gemv_rs<8, 2, 512, 16><<<dim3(43, 8, 2), 256, 0, stream>>>(hn, w1, w3, w3, scratch, FF_, D_);
  reduce_silu_k<<<86, 256, 0, stream>>>(scratch, gb);
  // 6) out = h + gb @ w2
  gemv_rs<8, 2, 344, 8><<<dim3(16, 32, 1), 256, 0, stream>>>(gb, w2, w2, w2, scratch, D_, FF_);
  reduceB_k<<<32, 256, 0, stream>>>(scratch, hbuf, out, 8192, 32);
}